// Round 13
// baseline (525.500 us; speedup 1.0000x reference)
//
#include <hip/hip_runtime.h>
#include <hip/hip_bf16.h>

#define NNODES 65536
#define NEDGES 262144
#define BATCH  64
#define HDIM   256
#define CAP    32           // list capacity per node (self-loop + edges)
#define NPBS   256          // nodes per k_sparse block -> 256 blocks
#define NSLAB  (NNODES / NPBS)   // 256 slabs

// ---------------------------------------------------------------------------
// K1: per-node u[n] = Wf[0:H] . x[n],  v[n] = Wf[H:2H] . x[n].
//     Side duty (spare early blocks): zero agg|deg (20480 float4) and compute
//     cnt via binary search (sorted node_batch). No runtime fill kernels.
// ---------------------------------------------------------------------------
__device__ __forceinline__ int lower_bound_batch(const int* nb, int key) {
  int lo = 0, hi = NNODES;
  while (lo < hi) {
    int mid = (lo + hi) >> 1;
    if (nb[mid] < key) lo = mid + 1; else hi = mid;
  }
  return lo;
}

__global__ __launch_bounds__(256) void k_uv(
    const float* __restrict__ hidden, const int* __restrict__ node_idx,
    const float* __restrict__ Wf, float* __restrict__ u, float* __restrict__ v,
    float* __restrict__ zbase, const int* __restrict__ node_batch,
    int* __restrict__ cnt) {
  if (blockIdx.x < 80) {                       // 80*256 = 20480 float4 = agg|deg
    int i = blockIdx.x * 256 + threadIdx.x;
    ((float4*)zbase)[i] = make_float4(0.f, 0.f, 0.f, 0.f);
  } else if (blockIdx.x == 80 && threadIdx.x < BATCH) {
    int b = threadIdx.x;
    int s0 = lower_bound_batch(node_batch, b);
    int s1 = lower_bound_batch(node_batch, b + 1);
    cnt[b] = s1 - s0;
  }
  int gw   = (blockIdx.x * 256 + threadIdx.x) >> 6;   // global wave = node
  int lane = threadIdx.x & 63;
  if (gw >= NNODES) return;
  const float4* xr = (const float4*)(hidden + (size_t)node_idx[gw] * HDIM);
  float4 xv = xr[lane];
  float4 wa = ((const float4*)Wf)[lane];
  float4 wb = ((const float4*)Wf)[64 + lane];
  float su = xv.x*wa.x + xv.y*wa.y + xv.z*wa.z + xv.w*wa.w;
  float sv = xv.x*wb.x + xv.y*wb.y + xv.z*wb.z + xv.w*wb.w;
  #pragma unroll
  for (int off = 32; off > 0; off >>= 1) {
    su += __shfl_down(su, off);
    sv += __shfl_down(sv, off);
  }
  if (lane == 0) { u[gw] = su; v[gw] = sv; }
}

// ---------------------------------------------------------------------------
// K2: per-edge filter weight w_e = sigmoid(u[row]+v[col]+bf); deg[col] += w_e
// ---------------------------------------------------------------------------
__global__ __launch_bounds__(256) void k_edge_w(
    const int* __restrict__ ei, const float* __restrict__ u,
    const float* __restrict__ v, const float* __restrict__ bf,
    float* __restrict__ wbuf, float* __restrict__ deg) {
  int e = blockIdx.x * 256 + threadIdx.x;
  if (e >= NEDGES) return;
  int r = ei[e], c = ei[NEDGES + e];
  float t = u[r] + v[c] + bf[0];
  float w = 1.0f / (1.0f + __expf(-t));
  wbuf[e] = w;
  unsafeAtomicAdd(&deg[c], w);
}

// ---------------------------------------------------------------------------
// K3: dis[n] = rsqrt(deg[n]+1); write the SELF-LOOP list entry (slot 0) and
//     init nodecnt[n]=1. Replaces the dense 16.8 MB t write entirely.
// ---------------------------------------------------------------------------
__global__ __launch_bounds__(256) void k_dis_list(
    const int* __restrict__ node_batch, const float* __restrict__ deg,
    float* __restrict__ dis, float2* __restrict__ list,
    int* __restrict__ nodecnt) {
  int n = blockIdx.x * 256 + threadIdx.x;
  if (n >= NNODES) return;
  float dn = rsqrtf(deg[n] + 1.0f);
  dis[n] = dn;
  int b = node_batch[n];
  list[(size_t)n * CAP] = make_float2(dn * dn, __int_as_float(b));
  nodecnt[n] = 1;
}

// ---------------------------------------------------------------------------
// K4: append edge coefficients to row r's list (thread-per-edge).
//     slot via per-node atomic counter (~4 appends/node: low contention).
// ---------------------------------------------------------------------------
__global__ __launch_bounds__(256) void k_t_list(
    const int* __restrict__ ei, const int* __restrict__ node_batch,
    const float* __restrict__ wbuf, const float* __restrict__ dis,
    float2* __restrict__ list, int* __restrict__ nodecnt) {
  int e = blockIdx.x * 256 + threadIdx.x;
  if (e >= NEDGES) return;
  int r = ei[e], c = ei[NEDGES + e];
  float coeff = dis[r] * wbuf[e] * dis[c];
  int b = node_batch[c];
  int slot = atomicAdd(&nodecnt[r], 1);
  if (slot < CAP)                              // P(overflow) ~ 1e-13, Poisson(4)
    list[(size_t)r * CAP + slot] = make_float2(coeff, __int_as_float(b));
}

// ---------------------------------------------------------------------------
// K5: SPARSE aggregation. Block owns 256 nodes; LDS-resident agg[64][256]
//     (64 KB) accumulated via ds_add_f32 (no-return -> no stalls).
//     Per node (one wave): 4 coalesced x-dword loads (j = lane+64q -> 2-way
//     banks, free), 1 lane-parallel list load broadcast via __shfl, ~5
//     entries x 4 ds-atomics. ~10x fewer LDS/VALU ops than the dense GEMM,
//     no 16.8 MB t read. Flush: plain coalesced stores to a private slab.
// ---------------------------------------------------------------------------
__global__ __launch_bounds__(1024) void k_sparse(
    const float* __restrict__ hidden, const int* __restrict__ node_idx,
    const float2* __restrict__ list, const int* __restrict__ nodecnt,
    float* __restrict__ part) {
  __shared__ float aggl[BATCH * HDIM];        // 64 KB
  int tid = threadIdx.x, lane = tid & 63, w = tid >> 6;   // 16 waves
  for (int i = tid; i < BATCH * HDIM; i += 1024) aggl[i] = 0.f;
  __syncthreads();

  int n0 = blockIdx.x * NPBS + w * (NPBS / 16);   // 16 nodes per wave
  for (int i = 0; i < NPBS / 16; ++i) {
    int n  = n0 + i;
    int cn = min(nodecnt[n], CAP);                 // wave-uniform
    const float* xr = hidden + (size_t)node_idx[n] * HDIM;
    float x0 = xr[lane];
    float x1 = xr[lane + 64];
    float x2 = xr[lane + 128];
    float x3 = xr[lane + 192];
    float2 ent = list[(size_t)n * CAP + (lane & (CAP - 1))];  // lane-parallel
    for (int e = 0; e < cn; ++e) {
      float cf = __shfl(ent.x, e);
      int   b  = __float_as_int(__shfl(ent.y, e));
      float* dst = aggl + b * HDIM;
      atomicAdd(&dst[lane],       cf * x0);   // ds_add_f32, fire-and-forget
      atomicAdd(&dst[lane + 64],  cf * x1);
      atomicAdd(&dst[lane + 128], cf * x2);
      atomicAdd(&dst[lane + 192], cf * x3);
    }
  }
  __syncthreads();
  float* myp = part + (size_t)blockIdx.x * (BATCH * HDIM);
  for (int i = tid; i < BATCH * HDIM; i += 1024) myp[i] = aggl[i];
}

// ---------------------------------------------------------------------------
// K5b: sum the 256 slabs -> agg[b][j].  4-way K-split; atomics into agg.
// ---------------------------------------------------------------------------
__global__ __launch_bounds__(256) void k_reduce(
    const float* __restrict__ part, float* __restrict__ agg) {
  int slice = blockIdx.x >> 6;                        // 0..3
  int i = (blockIdx.x & 63) * 256 + threadIdx.x;      // cell 0..16383
  float s0 = 0.f, s1 = 0.f, s2 = 0.f, s3 = 0.f;
  int k0 = slice * (NSLAB / 4);
  for (int k = k0; k < k0 + NSLAB / 4; k += 4) {
    s0 += part[(size_t)(k    ) * (BATCH * HDIM) + i];
    s1 += part[(size_t)(k + 1) * (BATCH * HDIM) + i];
    s2 += part[(size_t)(k + 2) * (BATCH * HDIM) + i];
    s3 += part[(size_t)(k + 3) * (BATCH * HDIM) + i];
  }
  unsafeAtomicAdd(&agg[i], (s0 + s1) + (s2 + s3));
}

// ---------------------------------------------------------------------------
// K6a: pooled[b][k] = (Wc[k,:] . agg[b,:]) / cnt[b] + bc[k]
//      one wave per output element (16384 waves = 4096 blocks)
// ---------------------------------------------------------------------------
__global__ __launch_bounds__(256) void k_mm1(
    const float* __restrict__ agg, const int* __restrict__ cnt,
    const float* __restrict__ Wc, const float* __restrict__ bc,
    float* __restrict__ pooled) {
  int gw   = (blockIdx.x * 256 + threadIdx.x) >> 6;   // 0..16383
  int lane = threadIdx.x & 63;
  int b = gw >> 8, k = gw & 255;
  float4 av = ((const float4*)(agg + (size_t)b * HDIM))[lane];
  float4 wv = ((const float4*)(Wc  + (size_t)k * HDIM))[lane];
  float p = av.x*wv.x + av.y*wv.y + av.z*wv.z + av.w*wv.w;
  #pragma unroll
  for (int off = 32; off > 0; off >>= 1) p += __shfl_down(p, off);
  if (lane == 0)
    pooled[(size_t)b * HDIM + k] = p / fmaxf((float)cnt[b], 1.0f) + bc[k];
}

// ---------------------------------------------------------------------------
// K6b: out[b][h] = tanh(Wd[h,:] . pooled[b,:] + bd[h])  -- same mapping
// ---------------------------------------------------------------------------
__global__ __launch_bounds__(256) void k_mm2(
    const float* __restrict__ pooled, const float* __restrict__ Wd,
    const float* __restrict__ bd, float* __restrict__ out) {
  int gw   = (blockIdx.x * 256 + threadIdx.x) >> 6;   // 0..16383
  int lane = threadIdx.x & 63;
  int b = gw >> 8, h = gw & 255;
  float4 av = ((const float4*)(pooled + (size_t)b * HDIM))[lane];
  float4 wv = ((const float4*)(Wd     + (size_t)h * HDIM))[lane];
  float p = av.x*wv.x + av.y*wv.y + av.z*wv.z + av.w*wv.w;
  #pragma unroll
  for (int off = 32; off > 0; off >>= 1) p += __shfl_down(p, off);
  if (lane == 0) out[(size_t)b * HDIM + h] = tanhf(p + bd[h]);
}

// ---------------------------------------------------------------------------
extern "C" void kernel_launch(void* const* d_in, const int* in_sizes, int n_in,
                              void* d_out, int out_size, void* d_ws, size_t ws_size,
                              hipStream_t stream) {
  const float* hidden     = (const float*)d_in[0];
  const int*   node_idx   = (const int*)  d_in[1];
  const int*   ei         = (const int*)  d_in[2];
  const int*   node_batch = (const int*)  d_in[3];
  const float* Wf         = (const float*)d_in[4];
  const float* bf         = (const float*)d_in[5];
  const float* Wc         = (const float*)d_in[6];
  const float* bc         = (const float*)d_in[7];
  const float* Wd         = (const float*)d_in[8];
  const float* bd         = (const float*)d_in[9];
  float* out = (float*)d_out;

  // workspace layout (floats)
  float*  ws      = (float*)d_ws;
  float2* list    = (float2*)ws;                       // N*CAP*2 floats (16.8 MB)
  float*  agg     = ws + (size_t)NNODES * CAP * 2;     // 16,384  ([b][j])
  float*  deg     = agg + BATCH * HDIM;                // 65,536  (agg|deg zeroed in k_uv)
  int*    cnt     = (int*)(deg + NNODES);              // 64      (written in k_uv)
  int*    nodecnt = cnt + 64;                          // 65,536  (fully written in k_dis_list)
  float*  u       = (float*)(nodecnt + NNODES);        // 65,536
  float*  v       = u + NNODES;                        // 65,536
  float*  dis     = v + NNODES;                        // 65,536
  float*  wbuf    = dis + NNODES;                      // 262,144
  float*  part    = wbuf + NEDGES;                     // 256*16,384 (16.8 MB)
  float*  pooled  = part + (size_t)NSLAB * BATCH * HDIM;  // 16,384

  // NO runtime fills: agg|deg zeroed + cnt computed inside k_uv's spare
  // blocks; nodecnt/list initialized by k_dis_list; part/pooled/u/v/dis/wbuf
  // fully overwritten every call.
  k_uv      <<<NNODES / 4,   256,  0, stream>>>(hidden, node_idx, Wf, u, v,
                                                agg, node_batch, cnt);
  k_edge_w  <<<NEDGES / 256, 256,  0, stream>>>(ei, u, v, bf, wbuf, deg);
  k_dis_list<<<NNODES / 256, 256,  0, stream>>>(node_batch, deg, dis, list, nodecnt);
  k_t_list  <<<NEDGES / 256, 256,  0, stream>>>(ei, node_batch, wbuf, dis, list, nodecnt);
  k_sparse  <<<NNODES / NPBS, 1024, 0, stream>>>(hidden, node_idx, list, nodecnt, part);
  k_reduce  <<<256,          256,  0, stream>>>(part, agg);
  k_mm1     <<<4096,         256,  0, stream>>>(agg, cnt, Wc, bc, pooled);
  k_mm2     <<<4096,         256,  0, stream>>>(pooled, Wd, bd, out);
}

// Round 14
// 171.638 us; speedup vs baseline: 3.0617x; 3.0617x over previous
//
#include <hip/hip_runtime.h>
#include <hip/hip_bf16.h>

#define NNODES 65536
#define NEDGES 262144
#define BATCH  64
#define HDIM   256
#define NPB    128              // nodes per k_gemm block -> 512 blocks (2/CU)
#define CK     16               // nodes per LDS chunk
#define NC     (NPB / CK)       // 8 chunks per block
#define NSLAB  (NNODES / NPB)   // 512 part slabs

// ---------------------------------------------------------------------------
// K1: per-node u[n] = Wf[0:H] . x[n],  v[n] = Wf[H:2H] . x[n].
//     Side duty (spare early blocks): zero deg (16384 float4) and compute
//     cnt via binary search (sorted node_batch). No runtime fill kernels.
// ---------------------------------------------------------------------------
__device__ __forceinline__ int lower_bound_batch(const int* nb, int key) {
  int lo = 0, hi = NNODES;
  while (lo < hi) {
    int mid = (lo + hi) >> 1;
    if (nb[mid] < key) lo = mid + 1; else hi = mid;
  }
  return lo;
}

__global__ __launch_bounds__(256) void k_uv(
    const float* __restrict__ hidden, const int* __restrict__ node_idx,
    const float* __restrict__ Wf, float* __restrict__ u, float* __restrict__ v,
    float* __restrict__ deg, const int* __restrict__ node_batch,
    int* __restrict__ cnt) {
  if (blockIdx.x < 64) {                       // 64*256 = 16384 float4 = deg
    int i = blockIdx.x * 256 + threadIdx.x;
    ((float4*)deg)[i] = make_float4(0.f, 0.f, 0.f, 0.f);
  } else if (blockIdx.x == 64 && threadIdx.x < BATCH) {
    int b = threadIdx.x;
    int s0 = lower_bound_batch(node_batch, b);
    int s1 = lower_bound_batch(node_batch, b + 1);
    cnt[b] = s1 - s0;
  }
  int gw   = (blockIdx.x * 256 + threadIdx.x) >> 6;   // global wave = node
  int lane = threadIdx.x & 63;
  if (gw >= NNODES) return;
  const float4* xr = (const float4*)(hidden + (size_t)node_idx[gw] * HDIM);
  float4 xv = xr[lane];
  float4 wa = ((const float4*)Wf)[lane];
  float4 wb = ((const float4*)Wf)[64 + lane];
  float su = xv.x*wa.x + xv.y*wa.y + xv.z*wa.z + xv.w*wa.w;
  float sv = xv.x*wb.x + xv.y*wb.y + xv.z*wb.z + xv.w*wb.w;
  #pragma unroll
  for (int off = 32; off > 0; off >>= 1) {
    su += __shfl_down(su, off);
    sv += __shfl_down(sv, off);
  }
  if (lane == 0) { u[gw] = su; v[gw] = sv; }
}

// ---------------------------------------------------------------------------
// K2: per-edge filter weight w_e = sigmoid(u[row]+v[col]+bf); deg[col] += w_e
// ---------------------------------------------------------------------------
__global__ __launch_bounds__(256) void k_edge_w(
    const int* __restrict__ ei, const float* __restrict__ u,
    const float* __restrict__ v, const float* __restrict__ bf,
    float* __restrict__ wbuf, float* __restrict__ deg) {
  int e = blockIdx.x * 256 + threadIdx.x;
  if (e >= NEDGES) return;
  int r = ei[e], c = ei[NEDGES + e];
  float t = u[r] + v[c] + bf[0];
  float w = 1.0f / (1.0f + __expf(-t));
  wbuf[e] = w;
  unsafeAtomicAdd(&deg[c], w);    // GLOBAL fp atomic: native, fine (never LDS!)
}

// ---------------------------------------------------------------------------
// K3: dis[n] = rsqrt(deg[n]+1); write the FULL t row (zeros + self-loop value
//     at col node_batch[n]). 16 threads/node, 16B/thread, fully coalesced.
// ---------------------------------------------------------------------------
__global__ __launch_bounds__(256) void k_dis_t(
    const int* __restrict__ node_batch, const float* __restrict__ deg,
    float* __restrict__ dis, float* __restrict__ t) {
  int idx = blockIdx.x * 256 + threadIdx.x;   // 0 .. NNODES*16-1
  int n   = idx >> 4;
  int seg = idx & 15;                         // float4 segment within row
  float dn = rsqrtf(deg[n] + 1.0f);
  int b = node_batch[n];
  float4 val = make_float4(0.f, 0.f, 0.f, 0.f);
  if ((b >> 2) == seg) ((float*)&val)[b & 3] = dn * dn;
  *((float4*)(t + (size_t)n * BATCH + 4 * seg)) = val;
  if (seg == 0) dis[n] = dn;
}

// ---------------------------------------------------------------------------
// K4: scatter edge coefficients into t[row][batch[col]] (thread-per-edge).
// ---------------------------------------------------------------------------
__global__ __launch_bounds__(256) void k_t(
    const int* __restrict__ ei, const int* __restrict__ node_batch,
    const float* __restrict__ wbuf, const float* __restrict__ dis,
    float* __restrict__ t) {
  int e = blockIdx.x * 256 + threadIdx.x;
  if (e >= NEDGES) return;
  int r = ei[e], c = ei[NEDGES + e];
  float coeff = dis[r] * wbuf[e] * dis[c];
  int b = node_batch[c];
  unsafeAtomicAdd(&t[(size_t)r * BATCH + b], coeff);   // global, ~4/address
}

// ---------------------------------------------------------------------------
// K5: part[bid][b][j] = sum_{n in block} t[n][b] * x[n][j]
//     LDS double-buffer GEMM, NPB=128, 2 blocks/CU (proven R7/R8/R11 config).
//     Register accumulator only -- NO LDS atomics (R12 lesson: fp atomicAdd
//     on __shared__ lowers to a CAS loop, ~20x slowdown).
// ---------------------------------------------------------------------------
__global__ __launch_bounds__(1024, 2) void k_gemm(
    const float* __restrict__ hidden, const int* __restrict__ node_idx,
    const float* __restrict__ t, float* __restrict__ part) {
  __shared__ float xbuf[2][CK][HDIM];   // 32 KB
  __shared__ float tbuf[2][CK][BATCH];  //  8 KB
  int tid  = threadIdx.x;
  int lane = tid & 63;
  int wid  = tid >> 6;          // 0..15 = staged row within chunk; b-quad 4*wid
  int n0   = blockIdx.x * NPB;
  float acc[4][4] = {{0.f}};

  // prologue: stage chunk 0
  {
    int nid = node_idx[n0 + wid];
    float4 xr = *((const float4*)(hidden + (size_t)nid * HDIM) + lane);
    float  tr = t[(size_t)(n0 + wid) * BATCH + lane];
    *((float4*)&xbuf[0][wid][4 * lane]) = xr;
    tbuf[0][wid][lane] = tr;
  }

  for (int c = 0; c < NC; ++c) {
    __syncthreads();                       // buf[c&1] staged & visible
    float4 xr2; float tr2;
    if (c + 1 < NC) {
      int nid2 = node_idx[n0 + (c + 1) * CK + wid];
      xr2 = *((const float4*)(hidden + (size_t)nid2 * HDIM) + lane);
      tr2 = t[(size_t)(n0 + (c + 1) * CK + wid) * BATCH + lane];
      __builtin_amdgcn_sched_barrier(0);   // pin: don't sink these loads
    }
    #pragma unroll
    for (int k = 0; k < CK; ++k) {
      float4 tq = *((const float4*)&tbuf[c & 1][k][4 * wid]);   // uniform
      float4 xq = *((const float4*)&xbuf[c & 1][k][4 * lane]);  // dense
      acc[0][0] = fmaf(tq.x, xq.x, acc[0][0]);
      acc[0][1] = fmaf(tq.x, xq.y, acc[0][1]);
      acc[0][2] = fmaf(tq.x, xq.z, acc[0][2]);
      acc[0][3] = fmaf(tq.x, xq.w, acc[0][3]);
      acc[1][0] = fmaf(tq.y, xq.x, acc[1][0]);
      acc[1][1] = fmaf(tq.y, xq.y, acc[1][1]);
      acc[1][2] = fmaf(tq.y, xq.z, acc[1][2]);
      acc[1][3] = fmaf(tq.y, xq.w, acc[1][3]);
      acc[2][0] = fmaf(tq.z, xq.x, acc[2][0]);
      acc[2][1] = fmaf(tq.z, xq.y, acc[2][1]);
      acc[2][2] = fmaf(tq.z, xq.z, acc[2][2]);
      acc[2][3] = fmaf(tq.z, xq.w, acc[2][3]);
      acc[3][0] = fmaf(tq.w, xq.x, acc[3][0]);
      acc[3][1] = fmaf(tq.w, xq.y, acc[3][1]);
      acc[3][2] = fmaf(tq.w, xq.z, acc[3][2]);
      acc[3][3] = fmaf(tq.w, xq.w, acc[3][3]);
    }
    if (c + 1 < NC) {
      *((float4*)&xbuf[(c + 1) & 1][wid][4 * lane]) = xr2;
      tbuf[(c + 1) & 1][wid][lane] = tr2;
    }
  }

  float* myp = part + (size_t)blockIdx.x * (BATCH * HDIM);
  #pragma unroll
  for (int bi = 0; bi < 4; ++bi) {
    float4 o; o.x = acc[bi][0]; o.y = acc[bi][1]; o.z = acc[bi][2]; o.w = acc[bi][3];
    *((float4*)(myp + (size_t)(4 * wid + bi) * HDIM + 4 * lane)) = o;
  }
}

// ---------------------------------------------------------------------------
// K6: FUSED epilogue, one block per batch b (1024 threads).
//     phase 1: s_in[j]  = sum over 512 slabs of part[s][b][j] (4 thread-groups,
//              coalesced 1KB rows, 512KB/block, L2/L3-hot)
//     phase 2: s_mid[k] = (Wc[k,:].s_in)/cnt[b] + bc[k]   (16 waves x 16 dots)
//     phase 3: out[b,h] = tanh(Wd[h,:].s_mid + bd[h])     (16 waves x 16 dots)
//     Replaces k_reduce + k_mm1 + k_mm2: -2 stage boundaries, no agg/pooled
//     global roundtrips, no agg zeroing.
// ---------------------------------------------------------------------------
__global__ __launch_bounds__(1024) void k_final3(
    const float* __restrict__ part, const int* __restrict__ cnt,
    const float* __restrict__ Wc, const float* __restrict__ bc,
    const float* __restrict__ Wd, const float* __restrict__ bd,
    float* __restrict__ out) {
  __shared__ __align__(16) float s_part[4][HDIM];
  __shared__ __align__(16) float s_in[HDIM];
  __shared__ __align__(16) float s_mid[HDIM];
  int b = blockIdx.x, tid = threadIdx.x;
  int j = tid & 255, g = tid >> 8;            // 4 groups of 256 threads
  float s = 0.f;
  for (int sl = g; sl < NSLAB; sl += 4)       // group g takes slabs g, g+4, ...
    s += part[(size_t)sl * (BATCH * HDIM) + (size_t)b * HDIM + j];
  s_part[g][j] = s;
  __syncthreads();
  if (g == 0)
    s_in[j] = (s_part[0][j] + s_part[1][j]) + (s_part[2][j] + s_part[3][j]);
  __syncthreads();

  int lane = tid & 63, wid = tid >> 6;        // 16 waves
  float inv = 1.0f / fmaxf((float)cnt[b], 1.0f);
  float4 av = ((const float4*)s_in)[lane];
  #pragma unroll
  for (int kk = 0; kk < 16; ++kk) {
    int k = wid * 16 + kk;
    float4 wv = ((const float4*)(Wc + (size_t)k * HDIM))[lane];
    float p = av.x*wv.x + av.y*wv.y + av.z*wv.z + av.w*wv.w;
    #pragma unroll
    for (int off = 32; off > 0; off >>= 1) p += __shfl_down(p, off);
    if (lane == 0) s_mid[k] = p * inv + bc[k];
  }
  __syncthreads();
  float4 mv = ((const float4*)s_mid)[lane];
  #pragma unroll
  for (int kk = 0; kk < 16; ++kk) {
    int h = wid * 16 + kk;
    float4 wv = ((const float4*)(Wd + (size_t)h * HDIM))[lane];
    float p = mv.x*wv.x + mv.y*wv.y + mv.z*wv.z + mv.w*wv.w;
    #pragma unroll
    for (int off = 32; off > 0; off >>= 1) p += __shfl_down(p, off);
    if (lane == 0) out[(size_t)b * HDIM + h] = tanhf(p + bd[h]);
  }
}

// ---------------------------------------------------------------------------
extern "C" void kernel_launch(void* const* d_in, const int* in_sizes, int n_in,
                              void* d_out, int out_size, void* d_ws, size_t ws_size,
                              hipStream_t stream) {
  const float* hidden     = (const float*)d_in[0];
  const int*   node_idx   = (const int*)  d_in[1];
  const int*   ei         = (const int*)  d_in[2];
  const int*   node_batch = (const int*)  d_in[3];
  const float* Wf         = (const float*)d_in[4];
  const float* bf         = (const float*)d_in[5];
  const float* Wc         = (const float*)d_in[6];
  const float* bc         = (const float*)d_in[7];
  const float* Wd         = (const float*)d_in[8];
  const float* bd         = (const float*)d_in[9];
  float* out = (float*)d_out;

  // workspace layout (floats)
  float* ws   = (float*)d_ws;
  float* t    = ws;                               // 4,194,304  (16.8 MB)
  float* deg  = t + (size_t)NNODES * BATCH;       // 65,536  (zeroed in k_uv)
  int*   cnt  = (int*)(deg + NNODES);             // 64      (written in k_uv)
  float* u    = (float*)(cnt + 64);               // 65,536
  float* v    = u + NNODES;                       // 65,536
  float* dis  = v + NNODES;                       // 65,536
  float* wbuf = dis + NNODES;                     // 262,144
  float* part = wbuf + NEDGES;                    // 512*16,384 (33.6 MB)

  // NO runtime fills: deg zeroed + cnt computed inside k_uv's spare blocks;
  // t fully written by k_dis_t; u/v/dis/wbuf/part fully overwritten per call.
  k_uv    <<<NNODES / 4,        256,  0, stream>>>(hidden, node_idx, Wf, u, v,
                                                   deg, node_batch, cnt);
  k_edge_w<<<NEDGES / 256,      256,  0, stream>>>(ei, u, v, bf, wbuf, deg);
  k_dis_t <<<NNODES * 16 / 256, 256,  0, stream>>>(node_batch, deg, dis, t);
  k_t     <<<NEDGES / 256,      256,  0, stream>>>(ei, node_batch, wbuf, dis, t);
  k_gemm  <<<NNODES / NPB,      1024, 0, stream>>>(hidden, node_idx, t, part);
  k_final3<<<BATCH,             1024, 0, stream>>>(part, cnt, Wc, bc, Wd, bd, out);
}

// Round 15
// 122.841 us; speedup vs baseline: 4.2779x; 1.3972x over previous
//
#include <hip/hip_runtime.h>
#include <hip/hip_bf16.h>

#define NNODES 65536
#define NEDGES 262144
#define BATCH  64
#define HDIM   256
#define NPB    128          // nodes per k_gemm block -> 512 blocks (2/CU)
#define CK     16           // nodes per LDS chunk
#define NC     (NPB / CK)   // 8 chunks per block

// ---------------------------------------------------------------------------
// K1: per-node u[n] = Wf[0:H] . x[n],  v[n] = Wf[H:2H] . x[n].
//     Side duty (spare early blocks): zero agg|deg (20480 float4) and compute
//     cnt via binary search -- no runtime fill kernels in the graph.
// ---------------------------------------------------------------------------
__device__ __forceinline__ int lower_bound_batch(const int* nb, int key) {
  int lo = 0, hi = NNODES;
  while (lo < hi) {
    int mid = (lo + hi) >> 1;
    if (nb[mid] < key) lo = mid + 1; else hi = mid;
  }
  return lo;
}

__global__ __launch_bounds__(256) void k_uv(
    const float* __restrict__ hidden, const int* __restrict__ node_idx,
    const float* __restrict__ Wf, float* __restrict__ u, float* __restrict__ v,
    float* __restrict__ zbase, const int* __restrict__ node_batch,
    int* __restrict__ cnt) {
  if (blockIdx.x < 80) {                       // 80*256 = 20480 float4 = agg|deg
    int i = blockIdx.x * 256 + threadIdx.x;
    ((float4*)zbase)[i] = make_float4(0.f, 0.f, 0.f, 0.f);
  } else if (blockIdx.x == 80 && threadIdx.x < BATCH) {
    int b = threadIdx.x;
    int s0 = lower_bound_batch(node_batch, b);
    int s1 = lower_bound_batch(node_batch, b + 1);
    cnt[b] = s1 - s0;
  }
  int gw   = (blockIdx.x * 256 + threadIdx.x) >> 6;   // global wave = node
  int lane = threadIdx.x & 63;
  if (gw >= NNODES) return;
  const float4* xr = (const float4*)(hidden + (size_t)node_idx[gw] * HDIM);
  float4 xv = xr[lane];
  float4 wa = ((const float4*)Wf)[lane];
  float4 wb = ((const float4*)Wf)[64 + lane];
  float su = xv.x*wa.x + xv.y*wa.y + xv.z*wa.z + xv.w*wa.w;
  float sv = xv.x*wb.x + xv.y*wb.y + xv.z*wb.z + xv.w*wb.w;
  #pragma unroll
  for (int off = 32; off > 0; off >>= 1) {
    su += __shfl_down(su, off);
    sv += __shfl_down(sv, off);
  }
  if (lane == 0) { u[gw] = su; v[gw] = sv; }
}

// ---------------------------------------------------------------------------
// K2: per-edge filter weight w_e = sigmoid(u[row]+v[col]+bf); deg[col] += w_e
// ---------------------------------------------------------------------------
__global__ __launch_bounds__(256) void k_edge_w(
    const int* __restrict__ ei, const float* __restrict__ u,
    const float* __restrict__ v, const float* __restrict__ bf,
    float* __restrict__ wbuf, float* __restrict__ deg) {
  int e = blockIdx.x * 256 + threadIdx.x;
  if (e >= NEDGES) return;
  int r = ei[e], c = ei[NEDGES + e];
  float t = u[r] + v[c] + bf[0];
  float w = 1.0f / (1.0f + __expf(-t));
  wbuf[e] = w;
  unsafeAtomicAdd(&deg[c], w);    // GLOBAL fp atomic: native (never on LDS!)
}

// ---------------------------------------------------------------------------
// K3: dis[n] = rsqrt(deg[n]+1); write the FULL t row (zeros + self-loop value
//     at col node_batch[n]). 16 threads/node, 16B/thread, fully coalesced.
// ---------------------------------------------------------------------------
__global__ __launch_bounds__(256) void k_dis_t(
    const int* __restrict__ node_batch, const float* __restrict__ deg,
    float* __restrict__ dis, float* __restrict__ t) {
  int idx = blockIdx.x * 256 + threadIdx.x;   // 0 .. NNODES*16-1
  int n   = idx >> 4;
  int seg = idx & 15;                         // float4 segment within row
  float dn = rsqrtf(deg[n] + 1.0f);
  int b = node_batch[n];
  float4 val = make_float4(0.f, 0.f, 0.f, 0.f);
  if ((b >> 2) == seg) ((float*)&val)[b & 3] = dn * dn;
  *((float4*)(t + (size_t)n * BATCH + 4 * seg)) = val;
  if (seg == 0) dis[n] = dn;
}

// ---------------------------------------------------------------------------
// K4: scatter edge coefficients into t[row][batch[col]] (thread-per-edge).
// ---------------------------------------------------------------------------
__global__ __launch_bounds__(256) void k_t(
    const int* __restrict__ ei, const int* __restrict__ node_batch,
    const float* __restrict__ wbuf, const float* __restrict__ dis,
    float* __restrict__ t) {
  int e = blockIdx.x * 256 + threadIdx.x;
  if (e >= NEDGES) return;
  int r = ei[e], c = ei[NEDGES + e];
  float coeff = dis[r] * wbuf[e] * dis[c];
  int b = node_batch[c];
  unsafeAtomicAdd(&t[(size_t)r * BATCH + b], coeff);   // global, ~4/address
}

// ---------------------------------------------------------------------------
// K5: part[bid][b][j] = sum_{n in block} t[n][b] * x[n][j]
//     LDS double-buffer GEMM, NPB=128, 2 blocks/CU = 32 waves/CU (max occ).
//     Register accumulator only -- NO LDS fp atomics (R12: CAS-loop, 20x).
// ---------------------------------------------------------------------------
__global__ __launch_bounds__(1024, 2) void k_gemm(
    const float* __restrict__ hidden, const int* __restrict__ node_idx,
    const float* __restrict__ t, float* __restrict__ part) {
  __shared__ float xbuf[2][CK][HDIM];   // 32 KB
  __shared__ float tbuf[2][CK][BATCH];  //  8 KB
  int tid  = threadIdx.x;
  int lane = tid & 63;
  int wid  = tid >> 6;          // 0..15 = staged row within chunk; b-quad 4*wid
  int n0   = blockIdx.x * NPB;
  float acc[4][4] = {{0.f}};

  // prologue: stage chunk 0
  {
    int nid = node_idx[n0 + wid];
    float4 xr = *((const float4*)(hidden + (size_t)nid * HDIM) + lane);
    float  tr = t[(size_t)(n0 + wid) * BATCH + lane];
    *((float4*)&xbuf[0][wid][4 * lane]) = xr;
    tbuf[0][wid][lane] = tr;
  }

  for (int c = 0; c < NC; ++c) {
    __syncthreads();                       // buf[c&1] staged & visible
    float4 xr2; float tr2;
    if (c + 1 < NC) {
      int nid2 = node_idx[n0 + (c + 1) * CK + wid];
      xr2 = *((const float4*)(hidden + (size_t)nid2 * HDIM) + lane);
      tr2 = t[(size_t)(n0 + (c + 1) * CK + wid) * BATCH + lane];
      __builtin_amdgcn_sched_barrier(0);   // pin: don't sink these loads
    }
    #pragma unroll
    for (int k = 0; k < CK; ++k) {
      float4 tq = *((const float4*)&tbuf[c & 1][k][4 * wid]);   // uniform
      float4 xq = *((const float4*)&xbuf[c & 1][k][4 * lane]);  // dense
      acc[0][0] = fmaf(tq.x, xq.x, acc[0][0]);
      acc[0][1] = fmaf(tq.x, xq.y, acc[0][1]);
      acc[0][2] = fmaf(tq.x, xq.z, acc[0][2]);
      acc[0][3] = fmaf(tq.x, xq.w, acc[0][3]);
      acc[1][0] = fmaf(tq.y, xq.x, acc[1][0]);
      acc[1][1] = fmaf(tq.y, xq.y, acc[1][1]);
      acc[1][2] = fmaf(tq.y, xq.z, acc[1][2]);
      acc[1][3] = fmaf(tq.y, xq.w, acc[1][3]);
      acc[2][0] = fmaf(tq.z, xq.x, acc[2][0]);
      acc[2][1] = fmaf(tq.z, xq.y, acc[2][1]);
      acc[2][2] = fmaf(tq.z, xq.z, acc[2][2]);
      acc[2][3] = fmaf(tq.z, xq.w, acc[2][3]);
      acc[3][0] = fmaf(tq.w, xq.x, acc[3][0]);
      acc[3][1] = fmaf(tq.w, xq.y, acc[3][1]);
      acc[3][2] = fmaf(tq.w, xq.z, acc[3][2]);
      acc[3][3] = fmaf(tq.w, xq.w, acc[3][3]);
    }
    if (c + 1 < NC) {
      *((float4*)&xbuf[(c + 1) & 1][wid][4 * lane]) = xr2;
      tbuf[(c + 1) & 1][wid][lane] = tr2;
    }
  }

  float* myp = part + (size_t)blockIdx.x * (BATCH * HDIM);
  #pragma unroll
  for (int bi = 0; bi < 4; ++bi) {
    float4 o; o.x = acc[bi][0]; o.y = acc[bi][1]; o.z = acc[bi][2]; o.w = acc[bi][3];
    *((float4*)(myp + (size_t)(4 * wid + bi) * HDIM + 4 * lane)) = o;
  }
}

// ---------------------------------------------------------------------------
// K5b: sum the 512 slabs -> agg[b][j]. 256 blocks, 4-way K-split, 4
//      independent accumulators (load-pipelineable, unlike the fused R13).
// ---------------------------------------------------------------------------
__global__ __launch_bounds__(256) void k_reduce(
    const float* __restrict__ part, float* __restrict__ agg) {
  int slice = blockIdx.x >> 6;                        // 0..3
  int i = (blockIdx.x & 63) * 256 + threadIdx.x;      // cell 0..16383
  float s0 = 0.f, s1 = 0.f, s2 = 0.f, s3 = 0.f;
  int k0 = slice * 128;
  for (int k = k0; k < k0 + 128; k += 4) {
    s0 += part[(size_t)(k    ) * (BATCH * HDIM) + i];
    s1 += part[(size_t)(k + 1) * (BATCH * HDIM) + i];
    s2 += part[(size_t)(k + 2) * (BATCH * HDIM) + i];
    s3 += part[(size_t)(k + 3) * (BATCH * HDIM) + i];
  }
  unsafeAtomicAdd(&agg[i], (s0 + s1) + (s2 + s3));
}

// ---------------------------------------------------------------------------
// K6a: pooled[b][k] = (Wc[k,:] . agg[b,:]) / cnt[b] + bc[k]
//      one wave per output element (16384 waves = 4096 blocks)
// ---------------------------------------------------------------------------
__global__ __launch_bounds__(256) void k_mm1(
    const float* __restrict__ agg, const int* __restrict__ cnt,
    const float* __restrict__ Wc, const float* __restrict__ bc,
    float* __restrict__ pooled) {
  int gw   = (blockIdx.x * 256 + threadIdx.x) >> 6;   // 0..16383
  int lane = threadIdx.x & 63;
  int b = gw >> 8, k = gw & 255;
  float4 av = ((const float4*)(agg + (size_t)b * HDIM))[lane];
  float4 wv = ((const float4*)(Wc  + (size_t)k * HDIM))[lane];
  float p = av.x*wv.x + av.y*wv.y + av.z*wv.z + av.w*wv.w;
  #pragma unroll
  for (int off = 32; off > 0; off >>= 1) p += __shfl_down(p, off);
  if (lane == 0)
    pooled[(size_t)b * HDIM + k] = p / fmaxf((float)cnt[b], 1.0f) + bc[k];
}

// ---------------------------------------------------------------------------
// K6b: out[b][h] = tanh(Wd[h,:] . pooled[b,:] + bd[h])  -- same mapping
// ---------------------------------------------------------------------------
__global__ __launch_bounds__(256) void k_mm2(
    const float* __restrict__ pooled, const float* __restrict__ Wd,
    const float* __restrict__ bd, float* __restrict__ out) {
  int gw   = (blockIdx.x * 256 + threadIdx.x) >> 6;   // 0..16383
  int lane = threadIdx.x & 63;
  int b = gw >> 8, h = gw & 255;
  float4 av = ((const float4*)(pooled + (size_t)b * HDIM))[lane];
  float4 wv = ((const float4*)(Wd     + (size_t)h * HDIM))[lane];
  float p = av.x*wv.x + av.y*wv.y + av.z*wv.z + av.w*wv.w;
  #pragma unroll
  for (int off = 32; off > 0; off >>= 1) p += __shfl_down(p, off);
  if (lane == 0) out[(size_t)b * HDIM + h] = tanhf(p + bd[h]);
}

// ---------------------------------------------------------------------------
extern "C" void kernel_launch(void* const* d_in, const int* in_sizes, int n_in,
                              void* d_out, int out_size, void* d_ws, size_t ws_size,
                              hipStream_t stream) {
  const float* hidden     = (const float*)d_in[0];
  const int*   node_idx   = (const int*)  d_in[1];
  const int*   ei         = (const int*)  d_in[2];
  const int*   node_batch = (const int*)  d_in[3];
  const float* Wf         = (const float*)d_in[4];
  const float* bf         = (const float*)d_in[5];
  const float* Wc         = (const float*)d_in[6];
  const float* bc         = (const float*)d_in[7];
  const float* Wd         = (const float*)d_in[8];
  const float* bd         = (const float*)d_in[9];
  float* out = (float*)d_out;

  // workspace layout (floats)
  float* ws     = (float*)d_ws;
  float* t      = ws;                               // 4,194,304  (16.8 MB)
  float* agg    = t + (size_t)NNODES * BATCH;       // 16,384     ([b][j])
  float* deg    = agg + BATCH * HDIM;               // 65,536     (agg|deg zeroed in k_uv)
  int*   cnt    = (int*)(deg + NNODES);             // 64         (written in k_uv)
  float* u      = (float*)(cnt + 64);               // 65,536
  float* v      = u + NNODES;                       // 65,536
  float* dis    = v + NNODES;                       // 65,536
  float* wbuf   = dis + NNODES;                     // 262,144
  float* part   = wbuf + NEDGES;                    // 512*16,384 (33.6 MB)
  float* pooled = part + (size_t)(NNODES / NPB) * BATCH * HDIM;  // 16,384

  // NO runtime fills: agg|deg zeroed + cnt computed inside k_uv's spare
  // blocks; t fully written by k_dis_t; u/v/dis/wbuf/part/pooled fully
  // overwritten every call.
  k_uv    <<<NNODES / 4,        256,  0, stream>>>(hidden, node_idx, Wf, u, v,
                                                   agg, node_batch, cnt);
  k_edge_w<<<NEDGES / 256,      256,  0, stream>>>(ei, u, v, bf, wbuf, deg);
  k_dis_t <<<NNODES * 16 / 256, 256,  0, stream>>>(node_batch, deg, dis, t);
  k_t     <<<NEDGES / 256,      256,  0, stream>>>(ei, node_batch, wbuf, dis, t);
  k_gemm  <<<NNODES / NPB,      1024, 0, stream>>>(hidden, node_idx, t, part);
  k_reduce<<<256,               256,  0, stream>>>(part, agg);
  k_mm1   <<<4096,              256,  0, stream>>>(agg, cnt, Wc, bc, pooled);
  k_mm2   <<<4096,              256,  0, stream>>>(pooled, Wd, bd, out);
}